// Round 1
// baseline (1023.981 us; speedup 1.0000x reference)
//
#include <hip/hip_runtime.h>
#include <stdint.h>

#define N_HEADS 8
#define IN_DIM 1024
#define ATTN_DIM 128
#define OUT_DIM 1024
#define BATCH 32768

typedef float  floatx4 __attribute__((ext_vector_type(4)));
typedef short  short8  __attribute__((ext_vector_type(8)));

__device__ __forceinline__ unsigned short f2b(float f) {
  union { float f; uint32_t u; } c; c.f = f;
  uint32_t u = c.u;
  uint32_t r = (u + 0x7FFFu + ((u >> 16) & 1u)) >> 16;  // RNE
  return (unsigned short)r;
}
__device__ __forceinline__ float b2f(unsigned short b) {
  union { uint32_t u; float f; } c; c.u = ((uint32_t)b) << 16;
  return c.f;
}

__device__ __forceinline__ void load_lds16(const void* g, void* l) {
  __builtin_amdgcn_global_load_lds((__attribute__((address_space(1))) void*)g,
                                   (__attribute__((address_space(3))) void*)l,
                                   16, 0, 0);
}

// ---------------- legacy 128x128 machinery (phase1 + fallbacks) ----------------

template<bool BF>
__device__ __forceinline__ void stage_tile(const unsigned short* gb, const float* gf,
                                           int ld, size_t row0, int kt,
                                           unsigned short* lds, int tid) {
  if constexpr (BF) {
    const unsigned short* g = gb + row0 * (size_t)ld + kt;
    int w = tid >> 6, lane = tid & 63;
    int lrow = lane >> 3;
    int lchunk = (lane & 7) ^ lrow;
#pragma unroll
    for (int r = 0; r < 4; r++) {
      int rowblk = w * 8 + r * 32;
      const unsigned short* gp = g + (size_t)(rowblk + lrow) * ld + lchunk * 8;
      load_lds16(gp, lds + (size_t)rowblk * 64);
    }
  } else {
    const float* g = gf + row0 * (size_t)ld + kt;
#pragma unroll
    for (int it = 0; it < 8; it++) {
      int idx = it * 1024 + tid * 4;
      int row = idx >> 6, col = idx & 63;
      int sc = (((col >> 3) ^ (row & 7)) << 3) + (col & 7);
      float4 v = *(const float4*)(g + (size_t)row * ld + col);
      *(ushort4*)(lds + row * 64 + sc) =
          make_ushort4(f2b(v.x), f2b(v.y), f2b(v.z), f2b(v.w));
    }
  }
}

__device__ __forceinline__ void mma_tile(const unsigned short* Xs, const unsigned short* Ws,
                                         floatx4 acc[4][4], int wr, int wc, int lq, int lr) {
#pragma unroll
  for (int s = 0; s < 2; s++) {
    short8 a[4], b[4];
    int ch = ((4 * s + lq) ^ (lr & 7)) * 8;
#pragma unroll
    for (int i = 0; i < 4; i++)
      a[i] = *(const short8*)(Xs + (64 * wr + 16 * i + lr) * 64 + ch);
#pragma unroll
    for (int j = 0; j < 4; j++)
      b[j] = *(const short8*)(Ws + (64 * wc + 16 * j + lr) * 64 + ch);
#pragma unroll
    for (int i = 0; i < 4; i++)
#pragma unroll
      for (int j = 0; j < 4; j++)
        acc[i][j] = __builtin_amdgcn_mfma_f32_16x16x32_bf16(a[i], b[j], acc[i][j], 0, 0, 0);
  }
}

// ---- Phase 1a: Q = x@Wq^T + bq, stored bf16 into Qb (ws scratch) ----
__launch_bounds__(256, 2)
__global__ void q_gemm(const unsigned short* __restrict__ xb,
                       const unsigned short* __restrict__ wqb,
                       const float* __restrict__ bq, unsigned short* __restrict__ Qb) {
  __shared__ unsigned short Xs[128 * 64];
  __shared__ unsigned short Ws[128 * 64];
  int tid = threadIdx.x;
  size_t row0 = (size_t)blockIdx.x * 128;
  int w = tid >> 6, lane = tid & 63;
  int wr = w >> 1, wc = w & 1, lq = lane >> 4, lr = lane & 15;

  floatx4 acc[4][4];
#pragma unroll
  for (int i = 0; i < 4; i++)
#pragma unroll
    for (int j = 0; j < 4; j++) acc[i][j] = (floatx4){0.f, 0.f, 0.f, 0.f};

  for (int kt = 0; kt < IN_DIM; kt += 64) {
    stage_tile<true>(xb, nullptr, IN_DIM, row0, kt, Xs, tid);
    stage_tile<true>(wqb, nullptr, IN_DIM, 0, kt, Ws, tid);
    __syncthreads();
    mma_tile(Xs, Ws, acc, wr, wc, lq, lr);
    __syncthreads();
  }
#pragma unroll
  for (int i = 0; i < 4; i++)
#pragma unroll
    for (int j = 0; j < 4; j++)
#pragma unroll
      for (int r = 0; r < 4; r++) {
        int row_l = 64 * wr + 16 * i + 4 * lq + r;
        int col_l = 64 * wc + 16 * j + lr;
        Qb[(row0 + row_l) * 128 + col_l] = f2b(acc[i][j][r] + bq[col_l]);
      }
}

// ---- Phase 1b: per (tile, head): K = x@Wk_h^T, dots[r,h] = sum_c (K+bk)*Q ----
__launch_bounds__(256, 2)
__global__ void k_dot(const unsigned short* __restrict__ xb,
                      const unsigned short* __restrict__ wkb,
                      const unsigned short* __restrict__ Qb,
                      const float* __restrict__ bk, float* __restrict__ dots) {
  __shared__ unsigned short Xs[128 * 64];
  __shared__ unsigned short Ws[128 * 64];
  __shared__ float dsum[128];
  int b = blockIdx.x;
  int bt = (b >> 6) * 8 + (b & 7);
  int h  = (b >> 3) & 7;
  size_t row0 = (size_t)bt * 128;
  int tid = threadIdx.x;
  int w = tid >> 6, lane = tid & 63;
  int wr = w >> 1, wc = w & 1, lq = lane >> 4, lr = lane & 15;

  if (tid < 128) dsum[tid] = 0.0f;

  floatx4 acc[4][4];
#pragma unroll
  for (int i = 0; i < 4; i++)
#pragma unroll
    for (int j = 0; j < 4; j++) acc[i][j] = (floatx4){0.f, 0.f, 0.f, 0.f};

  const unsigned short* wkh = wkb + (size_t)h * ATTN_DIM * IN_DIM;
  for (int kt = 0; kt < IN_DIM; kt += 64) {
    stage_tile<true>(xb, nullptr, IN_DIM, row0, kt, Xs, tid);
    stage_tile<true>(wkh, nullptr, IN_DIM, 0, kt, Ws, tid);
    __syncthreads();
    mma_tile(Xs, Ws, acc, wr, wc, lq, lr);
    __syncthreads();
  }
#pragma unroll
  for (int i = 0; i < 4; i++)
#pragma unroll
    for (int r = 0; r < 4; r++) {
      int row_l = 64 * wr + 16 * i + 4 * lq + r;
      float p = 0.0f;
#pragma unroll
      for (int j = 0; j < 4; j++) {
        int col_l = 64 * wc + 16 * j + lr;
        p += (acc[i][j][r] + bk[h * ATTN_DIM + col_l]) *
             b2f(Qb[(row0 + row_l) * 128 + col_l]);
      }
      p += __shfl_xor(p, 1);
      p += __shfl_xor(p, 2);
      p += __shfl_xor(p, 4);
      p += __shfl_xor(p, 8);
      if (lr == 0) atomicAdd(&dsum[row_l], p);
    }
  __syncthreads();
  if (tid < 128) dots[(row0 + tid) * 8 + h] = dsum[tid];
}

// ---- Phase 1c: softmax over 8 heads, in place ----
__global__ void softmax8(float* __restrict__ dots) {
  int r = blockIdx.x * blockDim.x + threadIdx.x;
  float d[8];
  float m = -1e30f;
#pragma unroll
  for (int h = 0; h < 8; h++) {
    d[h] = dots[r * 8 + h] * 0.088388347648318447f;  // 1/sqrt(128)
    m = fmaxf(m, d[h]);
  }
  float s = 0.f;
#pragma unroll
  for (int h = 0; h < 8; h++) { d[h] = __expf(d[h] - m); s += d[h]; }
  float inv = 1.0f / s;
#pragma unroll
  for (int h = 0; h < 8; h++) dots[r * 8 + h] = d[h] * inv;
}

// =====================================================================
// Phase 2, deep-pipelined: single GEMM [B, 8*1024] x [8*1024, 1024].
// Heads concatenated on K; per-head scale a[b,h] folded by telescoped
// rescale at head boundaries: acc = acc*(a_{h-1}/a_h) + bv_h, final
// out = a_7 * acc.  256x256 tile, BK=32, 8 waves (2Mx4N, 128x64/wave),
// 4-deep LDS ring staged via global_load_lds, counted vmcnt(12) (T3+T4),
// XOR chunk swizzle on LDS (T2), setprio around MFMA cluster (T5),
// XCD-aware block swizzle (T1: 2 XCDs share one 4MB Wv col-panel = L2).
// =====================================================================

#define NT 256  // K-steps: 8*1024/32

__launch_bounds__(512, 2)
__global__ void attn_phase2_dp(const unsigned short* __restrict__ xb,
                               const unsigned short* __restrict__ wvb,
                               const float* __restrict__ bv,
                               const float* __restrict__ attn,
                               float* __restrict__ out) {
  __shared__ unsigned short Ab[4][256 * 32];  // 64 KB ring (A = x rows)
  __shared__ unsigned short Bb[4][256 * 32];  // 64 KB ring (B = Wv rows)
  __shared__ float Rs[256 * 8];   // [row][0]=a7 (final scale); [row][h>=1]=a_{h-1}/a_h
  __shared__ float bvs[8 * 256];  // [h][col]

  int bid = blockIdx.x;
  int wg = (bid & 7) * 64 + (bid >> 3);  // XCD swizzle: 64 consecutive wgs per XCD
  int ct = wg >> 7;                      // col-tile 0..3
  int rt = wg & 127;                     // row-tile 0..127
  size_t row0 = (size_t)rt * 256;
  int col0 = ct * 256;

  int tid = threadIdx.x;
  int w = tid >> 6, lane = tid & 63;
  int wr = w >> 2, wc = w & 3;           // 2M x 4N wave grid
  int lq = lane >> 4, lr = lane & 15;

  // ---- prologue: ratios + bias into LDS (all VMEM drained by __syncthreads
  // below, so main-loop vmcnt counting sees only global_load_lds) ----
  if (tid < 256) {
    const float* ap = attn + (row0 + tid) * 8;
    float a[8];
#pragma unroll
    for (int h = 0; h < 8; h++) a[h] = ap[h];
    Rs[tid * 8 + 0] = a[7];
#pragma unroll
    for (int h = 1; h < 8; h++) Rs[tid * 8 + h] = a[h - 1] / fmaxf(a[h], 1e-30f);
  }
  for (int i = tid; i < 2048; i += 512)
    bvs[i] = bv[(i >> 8) * OUT_DIM + col0 + (i & 255)];
  __syncthreads();

  // acc init = bv_0 (head-0 bias; S_0 = bv_0 + G_0)
  floatx4 acc[8][4];
  {
    float bv0[4];
#pragma unroll
    for (int n = 0; n < 4; n++) bv0[n] = bvs[wc * 64 + 16 * n + lr];
#pragma unroll
    for (int m = 0; m < 8; m++)
#pragma unroll
      for (int n = 0; n < 4; n++) acc[m][n] = (floatx4){bv0[0], bv0[0], bv0[0], bv0[0]},
                                  acc[m][n] = (floatx4){bv0[n], bv0[n], bv0[n], bv0[n]};
  }

  // ---- staging geometry: per K-step 4 quanta of 8KB (A lo/hi, B lo/hi);
  // each wave = 1 gload_lds per quantum (1KB, 16 rows x 32k).
  // LDS[r][c] = G[r][c ^ ((r>>1)&3)]  (pre-swizzled global source) ----
  int srow = (w << 4) + (lane >> 2);                 // row within 128-row quantum
  int gch  = (lane & 3) ^ ((lane >> 3) & 3);         // pre-swizzled source chunk
  const unsigned short* xga = xb + (row0 + srow) * (size_t)IN_DIM + gch * 8;
  const unsigned short* xgb = xga + (size_t)128 * IN_DIM;
  const unsigned short* vga = wvb + (size_t)(col0 + srow) * IN_DIM + gch * 8;
  const unsigned short* vgb = vga + (size_t)128 * IN_DIM;

#define STAGE(T) do {                                                   \
    int _b = (T) & 3; int _kt = (T) << 5;                               \
    int _kc = _kt & 1023;                                               \
    size_t _vo = ((size_t)(_kt >> 10) << 20) + _kc;                     \
    load_lds16(xga + _kc, &Ab[_b][w * 16 * 32]);                        \
    load_lds16(xgb + _kc, &Ab[_b][(128 + w * 16) * 32]);                \
    load_lds16(vga + _vo, &Bb[_b][w * 16 * 32]);                        \
    load_lds16(vgb + _vo, &Bb[_b][(128 + w * 16) * 32]);                \
  } while (0)

  // fragment read offsets (conflict-free: chunk = lq ^ ((lr>>1)&3))
  int fsw = (lr >> 1) & 3;
  int fA = (wr * 128 + lr) * 32 + ((lq ^ fsw) * 8);
  int fB = (wc * 64 + lr) * 32 + ((lq ^ fsw) * 8);

#define RESCALE(H) do {                                                 \
    float _bh[4];                                                       \
    _Pragma("unroll") for (int n = 0; n < 4; n++)                       \
      _bh[n] = bvs[(H) * 256 + wc * 64 + 16 * n + lr];                  \
    _Pragma("unroll") for (int m = 0; m < 8; m++) {                     \
      _Pragma("unroll") for (int r = 0; r < 4; r++) {                   \
        float _rr = Rs[(wr * 128 + 16 * m + 4 * lq + r) * 8 + (H)];     \
        _Pragma("unroll") for (int n = 0; n < 4; n++)                   \
          acc[m][n][r] = acc[m][n][r] * _rr + _bh[n];                   \
      } } } while (0)

  // one K-step: stage tile T+3, wait tile T landed (counted vmcnt, never 0
  // in steady state), barrier (cross-wave visibility), ds_read frags,
  // optional head-boundary rescale, MFMA cluster under setprio, barrier
  // (frees ring slot T&3 for tile T+4).
#define PH(T, VM, STG) do {                                             \
    if (STG) STAGE((T) + 3);                                            \
    asm volatile("s_waitcnt vmcnt(" #VM ")" ::: "memory");              \
    __builtin_amdgcn_s_barrier();                                       \
    asm volatile("" ::: "memory");                                      \
    const unsigned short* _A = Ab[(T) & 3];                             \
    const unsigned short* _B = Bb[(T) & 3];                             \
    short8 a[8], b[4];                                                  \
    _Pragma("unroll") for (int m = 0; m < 8; m++)                       \
      a[m] = *(const short8*)(_A + fA + m * 512);                       \
    _Pragma("unroll") for (int n = 0; n < 4; n++)                       \
      b[n] = *(const short8*)(_B + fB + n * 512);                       \
    if ((((T) & 31) == 0) && (T)) RESCALE((T) >> 5);                    \
    __builtin_amdgcn_s_setprio(1);                                      \
    _Pragma("unroll") for (int m = 0; m < 8; m++)                       \
      _Pragma("unroll") for (int n = 0; n < 4; n++)                     \
        acc[m][n] = __builtin_amdgcn_mfma_f32_16x16x32_bf16(            \
            a[m], b[n], acc[m][n], 0, 0, 0);                            \
    __builtin_amdgcn_s_setprio(0);                                      \
    asm volatile("" ::: "memory");                                      \
    __builtin_amdgcn_s_barrier();                                       \
  } while (0)

  STAGE(0); STAGE(1); STAGE(2);
  for (int t = 0; t < NT - 3; ++t) PH(t, 12, 1);
  PH(NT - 3, 8, 0);
  PH(NT - 2, 4, 0);
  PH(NT - 1, 0, 0);
#undef PH
#undef RESCALE
#undef STAGE

  // epilogue: out = a_7 * S_7
#pragma unroll
  for (int m = 0; m < 8; m++)
#pragma unroll
    for (int r = 0; r < 4; r++) {
      int row = wr * 128 + 16 * m + 4 * lq + r;
      float fs = Rs[row * 8 + 0];
      float* op = out + (row0 + row) * (size_t)OUT_DIM + col0 + wc * 64 + lr;
#pragma unroll
      for (int n = 0; n < 4; n++) op[16 * n] = acc[m][n][r] * fs;
    }
}

// ---- legacy Phase 2 (float fallback only) ----
template<bool BF>
__launch_bounds__(256, 2)
__global__ void attn_phase2(const unsigned short* xb, const float* xf,
                            const unsigned short* wvb, const float* wvf,
                            const float* __restrict__ bv, const float* __restrict__ attn,
                            float* __restrict__ out) {
  __shared__ unsigned short Xs[128 * 64];
  __shared__ unsigned short Ws[128 * 64];
  __shared__ float As[128 * 8];
  __shared__ float bvs[8 * 128];
  int b = blockIdx.x;
  int bt = (b >> 6) * 8 + (b & 7);
  int ot = (b >> 3) & 7;
  size_t row0 = (size_t)bt * 128;
  int col0 = ot * 128;
  int tid = threadIdx.x;
  int w = tid >> 6, lane = tid & 63;
  int wr = w >> 1, wc = w & 1, lq = lane >> 4, lr = lane & 15;

  for (int i = tid; i < 1024; i += 256) {
    As[i]  = attn[row0 * 8 + i];
    bvs[i] = bv[(i >> 7) * OUT_DIM + col0 + (i & 127)];
  }
  __syncthreads();

  floatx4 oacc[4][4];
#pragma unroll
  for (int i = 0; i < 4; i++)
#pragma unroll
    for (int j = 0; j < 4; j++) oacc[i][j] = (floatx4){0.f, 0.f, 0.f, 0.f};

  for (int h = 0; h < N_HEADS; h++) {
    floatx4 acc[4][4];
#pragma unroll
    for (int i = 0; i < 4; i++)
#pragma unroll
      for (int j = 0; j < 4; j++) acc[i][j] = (floatx4){0.f, 0.f, 0.f, 0.f};
    for (int kt = 0; kt < IN_DIM; kt += 64) {
      stage_tile<BF>(xb, xf, IN_DIM, row0, kt, Xs, tid);
      if constexpr (BF)
        stage_tile<BF>(wvb + ((size_t)h * OUT_DIM + col0) * IN_DIM, nullptr, IN_DIM, 0, kt, Ws, tid);
      else
        stage_tile<BF>(nullptr, wvf + ((size_t)h * OUT_DIM + col0) * IN_DIM, IN_DIM, 0, kt, Ws, tid);
      __syncthreads();
      mma_tile(Xs, Ws, acc, wr, wc, lq, lr);
      __syncthreads();
    }
#pragma unroll
    for (int i = 0; i < 4; i++)
#pragma unroll
      for (int r = 0; r < 4; r++) {
        int row_l = 64 * wr + 16 * i + 4 * lq + r;
        float a = As[row_l * 8 + h];
#pragma unroll
        for (int j = 0; j < 4; j++) {
          int col_l = 64 * wc + 16 * j + lr;
          oacc[i][j][r] += a * (acc[i][j][r] + bvs[h * 128 + col_l]);
        }
      }
  }
#pragma unroll
  for (int i = 0; i < 4; i++)
#pragma unroll
    for (int r = 0; r < 4; r++) {
      int row_l = 64 * wr + 16 * i + 4 * lq + r;
#pragma unroll
      for (int j = 0; j < 4; j++) {
        int col_l = 64 * wc + 16 * j + lr;
        out[(row0 + row_l) * (size_t)OUT_DIM + col0 + col_l] = oacc[i][j][r];
      }
    }
}

// ---- fused phase 1 (fallback when ws can't hold Qb) ----
template<bool BF>
__launch_bounds__(256, 2)
__global__ void attn_phase1_fused(const unsigned short* xb, const float* xf,
                                  const unsigned short* wqb, const float* wqf,
                                  const unsigned short* wkb, const float* wkf,
                                  const float* bq, const float* bk, float* attn) {
  __shared__ unsigned short Xs[128 * 64];
  __shared__ unsigned short Ws[128 * 64];
  __shared__ unsigned short Qs[128 * 128];
  __shared__ float dots[128 * 8];
  int tid = threadIdx.x;
  size_t row0 = (size_t)blockIdx.x * 128;
  int w = tid >> 6, lane = tid & 63;
  int wr = w >> 1, wc = w & 1, lq = lane >> 4, lr = lane & 15;

  for (int i = tid; i < 1024; i += 256) dots[i] = 0.0f;

  floatx4 acc[4][4];
#pragma unroll
  for (int i = 0; i < 4; i++)
#pragma unroll
    for (int j = 0; j < 4; j++) acc[i][j] = (floatx4){0.f, 0.f, 0.f, 0.f};

  for (int kt = 0; kt < IN_DIM; kt += 64) {
    stage_tile<BF>(xb, xf, IN_DIM, row0, kt, Xs, tid);
    stage_tile<BF>(wqb, wqf, IN_DIM, 0, kt, Ws, tid);
    __syncthreads();
    mma_tile(Xs, Ws, acc, wr, wc, lq, lr);
    __syncthreads();
  }
#pragma unroll
  for (int i = 0; i < 4; i++)
#pragma unroll
    for (int j = 0; j < 4; j++)
#pragma unroll
      for (int r = 0; r < 4; r++) {
        int row_l = 64 * wr + 16 * i + 4 * lq + r;
        int col_l = 64 * wc + 16 * j + lr;
        Qs[row_l * 128 + col_l] = f2b(acc[i][j][r] + bq[col_l]);
      }
  __syncthreads();

  for (int h = 0; h < N_HEADS; h++) {
#pragma unroll
    for (int i = 0; i < 4; i++)
#pragma unroll
      for (int j = 0; j < 4; j++) acc[i][j] = (floatx4){0.f, 0.f, 0.f, 0.f};
    for (int kt = 0; kt < IN_DIM; kt += 64) {
      stage_tile<BF>(xb, xf, IN_DIM, row0, kt, Xs, tid);
      if constexpr (BF)
        stage_tile<BF>(wkb + (size_t)h * ATTN_DIM * IN_DIM, nullptr, IN_DIM, 0, kt, Ws, tid);
      else
        stage_tile<BF>(nullptr, wkf + (size_t)h * ATTN_DIM * IN_DIM, IN_DIM, 0, kt, Ws, tid);
      __syncthreads();
      mma_tile(Xs, Ws, acc, wr, wc, lq, lr);
      __syncthreads();
    }
#pragma unroll
    for (int i = 0; i < 4; i++)
#pragma unroll
      for (int r = 0; r < 4; r++) {
        int row_l = 64 * wr + 16 * i + 4 * lq + r;
        float p = 0.0f;
#pragma unroll
        for (int j = 0; j < 4; j++) {
          int col_l = 64 * wc + 16 * j + lr;
          p += (acc[i][j][r] + bk[h * ATTN_DIM + col_l]) * b2f(Qs[row_l * 128 + col_l]);
        }
        p += __shfl_xor(p, 1);
        p += __shfl_xor(p, 2);
        p += __shfl_xor(p, 4);
        p += __shfl_xor(p, 8);
        if (lr == 0) atomicAdd(&dots[row_l * 8 + h], p);
      }
    __syncthreads();
  }

  if (tid < 128) {
    float d[8];
    float m = -1e30f;
#pragma unroll
    for (int h = 0; h < 8; h++) {
      d[h] = dots[tid * 8 + h] * 0.088388347648318447f;
      m = fmaxf(m, d[h]);
    }
    float s = 0.f;
#pragma unroll
    for (int h = 0; h < 8; h++) { d[h] = __expf(d[h] - m); s += d[h]; }
    float inv = 1.0f / s;
    size_t rg = row0 + tid;
#pragma unroll
    for (int h = 0; h < 8; h++) attn[rg * 8 + h] = d[h] * inv;
  }
}

__global__ void cvt_bf16(const float4* __restrict__ in, ushort4* __restrict__ out, int n4) {
  int i = blockIdx.x * blockDim.x + threadIdx.x;
  int stride = gridDim.x * blockDim.x;
  for (; i < n4; i += stride) {
    float4 v = in[i];
    out[i] = make_ushort4(f2b(v.x), f2b(v.y), f2b(v.z), f2b(v.w));
  }
}

extern "C" void kernel_launch(void* const* d_in, const int* in_sizes, int n_in,
                              void* d_out, int out_size, void* d_ws, size_t ws_size,
                              hipStream_t stream) {
  const float* x  = (const float*)d_in[0];
  const float* Wq = (const float*)d_in[1];
  const float* bq = (const float*)d_in[2];
  const float* Wk = (const float*)d_in[3];
  const float* bk = (const float*)d_in[4];
  const float* Wv = (const float*)d_in[5];
  const float* bv = (const float*)d_in[6];
  float* out = (float*)d_out;

  // ws layout — d_out is NEVER used as scratch (its re-poison is not
  // reliably ordered against graph replays; see R2 post-mortem).
  char* ws = (char*)d_ws;
  float* attn = (float*)ws;                                        // dots -> attn in place
  size_t off = (size_t)BATCH * N_HEADS * 4;                        // 1 MB
  unsigned short* xb  = (unsigned short*)(ws + off); off += (size_t)BATCH * IN_DIM * 2;       // 64 MB
  unsigned short* wqb = (unsigned short*)(ws + off); off += (size_t)ATTN_DIM * IN_DIM * 2;    // 0.25 MB
  unsigned short* wkb = (unsigned short*)(ws + off); off += (size_t)N_HEADS * ATTN_DIM * IN_DIM * 2; // 2 MB
  unsigned short* wvb = (unsigned short*)(ws + off); off += (size_t)N_HEADS * OUT_DIM * IN_DIM * 2;  // 16 MB
  size_t off_noq = off;
  unsigned short* Qb  = (unsigned short*)(ws + off); off += (size_t)BATCH * ATTN_DIM * 2;     // 8 MB

  if (ws_size >= off_noq) {
    cvt_bf16<<<8192, 256, 0, stream>>>((const float4*)x,  (ushort4*)xb,  BATCH * IN_DIM / 4);
    cvt_bf16<<<128,  256, 0, stream>>>((const float4*)Wq, (ushort4*)wqb, ATTN_DIM * IN_DIM / 4);
    cvt_bf16<<<1024, 256, 0, stream>>>((const float4*)Wk, (ushort4*)wkb, N_HEADS * ATTN_DIM * IN_DIM / 4);
    cvt_bf16<<<8192, 256, 0, stream>>>((const float4*)Wv, (ushort4*)wvb, N_HEADS * OUT_DIM * IN_DIM / 4);
    if (ws_size >= off) {
      q_gemm<<<BATCH / 128, 256, 0, stream>>>(xb, wqb, bq, Qb);
      k_dot<<<(BATCH / 128) * N_HEADS, 256, 0, stream>>>(xb, wkb, Qb, bk, attn);
      softmax8<<<BATCH / 256, 256, 0, stream>>>(attn);
    } else {
      attn_phase1_fused<true><<<BATCH / 128, 256, 0, stream>>>(
          xb, nullptr, wqb, nullptr, wkb, nullptr, bq, bk, attn);
    }
    attn_phase2_dp<<<(BATCH / 256) * (OUT_DIM / 256), 512, 0, stream>>>(
        xb, wvb, bv, attn, out);
  } else {
    attn_phase1_fused<false><<<BATCH / 128, 256, 0, stream>>>(
        nullptr, x, nullptr, Wq, nullptr, Wk, bq, bk, attn);
    attn_phase2<false><<<(BATCH / 128) * (OUT_DIM / 128), 256, 0, stream>>>(
        nullptr, x, nullptr, Wv, bv, attn, out);
  }
}

// Round 2
// 840.479 us; speedup vs baseline: 1.2183x; 1.2183x over previous
//
#include <hip/hip_runtime.h>
#include <stdint.h>

#define N_HEADS 8
#define IN_DIM 1024
#define ATTN_DIM 128
#define OUT_DIM 1024
#define BATCH 32768

typedef float  floatx4 __attribute__((ext_vector_type(4)));
typedef short  short8  __attribute__((ext_vector_type(8)));

__device__ __forceinline__ unsigned short f2b(float f) {
  union { float f; uint32_t u; } c; c.f = f;
  uint32_t u = c.u;
  uint32_t r = (u + 0x7FFFu + ((u >> 16) & 1u)) >> 16;  // RNE
  return (unsigned short)r;
}
__device__ __forceinline__ float b2f(unsigned short b) {
  union { uint32_t u; float f; } c; c.u = ((uint32_t)b) << 16;
  return c.f;
}

__device__ __forceinline__ void load_lds16(const void* g, void* l) {
  __builtin_amdgcn_global_load_lds((__attribute__((address_space(1))) void*)g,
                                   (__attribute__((address_space(3))) void*)l,
                                   16, 0, 0);
}

// ---------------- legacy 128x128 machinery (phase1 + fallbacks) ----------------

template<bool BF>
__device__ __forceinline__ void stage_tile(const unsigned short* gb, const float* gf,
                                           int ld, size_t row0, int kt,
                                           unsigned short* lds, int tid) {
  if constexpr (BF) {
    const unsigned short* g = gb + row0 * (size_t)ld + kt;
    int w = tid >> 6, lane = tid & 63;
    int lrow = lane >> 3;
    int lchunk = (lane & 7) ^ lrow;
#pragma unroll
    for (int r = 0; r < 4; r++) {
      int rowblk = w * 8 + r * 32;
      const unsigned short* gp = g + (size_t)(rowblk + lrow) * ld + lchunk * 8;
      load_lds16(gp, lds + (size_t)rowblk * 64);
    }
  } else {
    const float* g = gf + row0 * (size_t)ld + kt;
#pragma unroll
    for (int it = 0; it < 8; it++) {
      int idx = it * 1024 + tid * 4;
      int row = idx >> 6, col = idx & 63;
      int sc = (((col >> 3) ^ (row & 7)) << 3) + (col & 7);
      float4 v = *(const float4*)(g + (size_t)row * ld + col);
      *(ushort4*)(lds + row * 64 + sc) =
          make_ushort4(f2b(v.x), f2b(v.y), f2b(v.z), f2b(v.w));
    }
  }
}

__device__ __forceinline__ void mma_tile(const unsigned short* Xs, const unsigned short* Ws,
                                         floatx4 acc[4][4], int wr, int wc, int lq, int lr) {
#pragma unroll
  for (int s = 0; s < 2; s++) {
    short8 a[4], b[4];
    int ch = ((4 * s + lq) ^ (lr & 7)) * 8;
#pragma unroll
    for (int i = 0; i < 4; i++)
      a[i] = *(const short8*)(Xs + (64 * wr + 16 * i + lr) * 64 + ch);
#pragma unroll
    for (int j = 0; j < 4; j++)
      b[j] = *(const short8*)(Ws + (64 * wc + 16 * j + lr) * 64 + ch);
#pragma unroll
    for (int i = 0; i < 4; i++)
#pragma unroll
      for (int j = 0; j < 4; j++)
        acc[i][j] = __builtin_amdgcn_mfma_f32_16x16x32_bf16(a[i], b[j], acc[i][j], 0, 0, 0);
  }
}

// ---- Phase 1a: Q = x@Wq^T + bq, stored bf16 into Qb (ws scratch) ----
__launch_bounds__(256, 2)
__global__ void q_gemm(const unsigned short* __restrict__ xb,
                       const unsigned short* __restrict__ wqb,
                       const float* __restrict__ bq, unsigned short* __restrict__ Qb) {
  __shared__ unsigned short Xs[128 * 64];
  __shared__ unsigned short Ws[128 * 64];
  int tid = threadIdx.x;
  size_t row0 = (size_t)blockIdx.x * 128;
  int w = tid >> 6, lane = tid & 63;
  int wr = w >> 1, wc = w & 1, lq = lane >> 4, lr = lane & 15;

  floatx4 acc[4][4];
#pragma unroll
  for (int i = 0; i < 4; i++)
#pragma unroll
    for (int j = 0; j < 4; j++) acc[i][j] = (floatx4){0.f, 0.f, 0.f, 0.f};

  for (int kt = 0; kt < IN_DIM; kt += 64) {
    stage_tile<true>(xb, nullptr, IN_DIM, row0, kt, Xs, tid);
    stage_tile<true>(wqb, nullptr, IN_DIM, 0, kt, Ws, tid);
    __syncthreads();
    mma_tile(Xs, Ws, acc, wr, wc, lq, lr);
    __syncthreads();
  }
#pragma unroll
  for (int i = 0; i < 4; i++)
#pragma unroll
    for (int j = 0; j < 4; j++)
#pragma unroll
      for (int r = 0; r < 4; r++) {
        int row_l = 64 * wr + 16 * i + 4 * lq + r;
        int col_l = 64 * wc + 16 * j + lr;
        Qb[(row0 + row_l) * 128 + col_l] = f2b(acc[i][j][r] + bq[col_l]);
      }
}

// ---- Phase 1b: per (tile, head): K = x@Wk_h^T, dots[r,h] = sum_c (K+bk)*Q ----
__launch_bounds__(256, 2)
__global__ void k_dot(const unsigned short* __restrict__ xb,
                      const unsigned short* __restrict__ wkb,
                      const unsigned short* __restrict__ Qb,
                      const float* __restrict__ bk, float* __restrict__ dots) {
  __shared__ unsigned short Xs[128 * 64];
  __shared__ unsigned short Ws[128 * 64];
  __shared__ float dsum[128];
  int b = blockIdx.x;
  int bt = (b >> 6) * 8 + (b & 7);
  int h  = (b >> 3) & 7;
  size_t row0 = (size_t)bt * 128;
  int tid = threadIdx.x;
  int w = tid >> 6, lane = tid & 63;
  int wr = w >> 1, wc = w & 1, lq = lane >> 4, lr = lane & 15;

  if (tid < 128) dsum[tid] = 0.0f;

  floatx4 acc[4][4];
#pragma unroll
  for (int i = 0; i < 4; i++)
#pragma unroll
    for (int j = 0; j < 4; j++) acc[i][j] = (floatx4){0.f, 0.f, 0.f, 0.f};

  const unsigned short* wkh = wkb + (size_t)h * ATTN_DIM * IN_DIM;
  for (int kt = 0; kt < IN_DIM; kt += 64) {
    stage_tile<true>(xb, nullptr, IN_DIM, row0, kt, Xs, tid);
    stage_tile<true>(wkh, nullptr, IN_DIM, 0, kt, Ws, tid);
    __syncthreads();
    mma_tile(Xs, Ws, acc, wr, wc, lq, lr);
    __syncthreads();
  }
#pragma unroll
  for (int i = 0; i < 4; i++)
#pragma unroll
    for (int r = 0; r < 4; r++) {
      int row_l = 64 * wr + 16 * i + 4 * lq + r;
      float p = 0.0f;
#pragma unroll
      for (int j = 0; j < 4; j++) {
        int col_l = 64 * wc + 16 * j + lr;
        p += (acc[i][j][r] + bk[h * ATTN_DIM + col_l]) *
             b2f(Qb[(row0 + row_l) * 128 + col_l]);
      }
      p += __shfl_xor(p, 1);
      p += __shfl_xor(p, 2);
      p += __shfl_xor(p, 4);
      p += __shfl_xor(p, 8);
      if (lr == 0) atomicAdd(&dsum[row_l], p);
    }
  __syncthreads();
  if (tid < 128) dots[(row0 + tid) * 8 + h] = dsum[tid];
}

// ---- Phase 1c: softmax over 8 heads, in place ----
__global__ void softmax8(float* __restrict__ dots) {
  int r = blockIdx.x * blockDim.x + threadIdx.x;
  float d[8];
  float m = -1e30f;
#pragma unroll
  for (int h = 0; h < 8; h++) {
    d[h] = dots[r * 8 + h] * 0.088388347648318447f;  // 1/sqrt(128)
    m = fmaxf(m, d[h]);
  }
  float s = 0.f;
#pragma unroll
  for (int h = 0; h < 8; h++) { d[h] = __expf(d[h] - m); s += d[h]; }
  float inv = 1.0f / s;
#pragma unroll
  for (int h = 0; h < 8; h++) dots[r * 8 + h] = d[h] * inv;
}

// =====================================================================
// Phase 2, m201-style 8-phase schedule: single GEMM [B, 8*1024]x[8*1024, 1024]
// (heads concatenated on K; per-head scale folded via telescoped rescale
//  acc = acc*(a_{h-1}/a_h) + bv_h at head boundaries, out = a_7*acc).
// BM=BN=256, BK=64, 512 thr = 8 waves (2M x 4N), per-wave 128x64.
// Per K-tile: 4 phases, each {ds_read quadrant; stage; bar; lgkm0;
// setprio1; 16 MFMA; setprio0; bar}.  Quadrants: (mlo,nlo),(mlo,nhi),
// (mhi,nhi),(mhi,nlo) -> 24 ds_read_b128/K-tile/wave, bLo regs carried.
// Staging: K-tile k+2's B at phase q2, A at q3 (WAR-safe: B(k) last read
// q1, A(k) last read q2, barrier-separated).  Steady-state vmcnt(8) once
// per K-tile (8 load-instructions = B(k+2)+A(k+2) in flight); epilogue
// drains 8 -> 0.  LDS XOR swizzle: granule g holds global chunk g^(row&7)
// (pre-swizzled global source; involution on read).  LDS 144KB -> 1 blk/CU.
// =====================================================================

#define NKT 128  // K-tiles: 8*1024/64

__launch_bounds__(512, 2)
__global__ void attn_phase2_8p(const unsigned short* __restrict__ xb,
                               const unsigned short* __restrict__ wvb,
                               const float* __restrict__ bv,
                               const float* __restrict__ attn,
                               float* __restrict__ out) {
  __shared__ unsigned short As_[2][2][128 * 64];  // [slot][half][row*64+col]
  __shared__ unsigned short Bs_[2][2][128 * 64];
  __shared__ float Rs[256 * 8];   // [row][0]=a7; [row][h>=1]=a_{h-1}/a_h
  __shared__ float bvs[8 * 256];  // [h][col]

  int bid = blockIdx.x;
  int wg = (bid & 7) * 64 + (bid >> 3);  // XCD swizzle: 64 consecutive wgs/XCD
  int ct = wg >> 7;                      // col-tile 0..3 (2 XCDs share B panel)
  int rt = wg & 127;                     // row-tile 0..127
  size_t row0 = (size_t)rt * 256;
  int col0 = ct * 256;

  int tid = threadIdx.x;
  int w = tid >> 6, lane = tid & 63;
  int wr = w >> 2, wc = w & 3;           // 2M x 4N wave grid
  int lq = lane >> 4, lr = lane & 15;

  // ---- prologue: ratios + bias into LDS ----
  if (tid < 256) {
    const float* ap = attn + (row0 + tid) * 8;
    float a[8];
#pragma unroll
    for (int h = 0; h < 8; h++) a[h] = ap[h];
    Rs[tid * 8 + 0] = a[7];
#pragma unroll
    for (int h = 1; h < 8; h++) Rs[tid * 8 + h] = a[h - 1] / fmaxf(a[h], 1e-30f);
  }
  for (int i = tid; i < 2048; i += 512)
    bvs[i] = bv[(i >> 8) * OUT_DIM + col0 + (i & 255)];
  __syncthreads();  // drains prologue vmem -> vmcnt counting below is clean

  // acc init = bv_0 (S_0 = G_0 + bv_0)
  floatx4 acc[8][4];
#pragma unroll
  for (int n = 0; n < 4; n++) {
    float b0 = bvs[wc * 64 + 16 * n + lr];
#pragma unroll
    for (int m = 0; m < 8; m++) acc[m][n] = (floatx4){b0, b0, b0, b0};
  }

  // ---- staging geometry: lane l covers row w*8+(l>>3), granule l&7 of a
  // 64-row quantum; fetched global chunk = (l&7)^(row&7) (pre-swizzle) ----
  int r8 = lane >> 3;
  int c8 = (lane & 7) ^ r8;
  const unsigned short* agbase = xb  + (row0 + w * 8 + r8) * (size_t)IN_DIM + c8 * 8;
  const unsigned short* bgbase = wvb + (size_t)(col0 + w * 8 + r8) * IN_DIM + c8 * 8;

#define STAGE_A(T) do {                                                  \
    int _s = (T) & 1;                                                    \
    const unsigned short* _g = agbase + (((T) & 15) << 6);               \
    load_lds16(_g,          &As_[_s][0][(w * 8) * 64]);                  \
    load_lds16(_g + 65536,  &As_[_s][0][(64 + w * 8) * 64]);             \
    load_lds16(_g + 131072, &As_[_s][1][(w * 8) * 64]);                  \
    load_lds16(_g + 196608, &As_[_s][1][(64 + w * 8) * 64]);             \
  } while (0)

#define STAGE_B(T) do {                                                  \
    int _s = (T) & 1;                                                    \
    const unsigned short* _g = bgbase +                                  \
        (((size_t)((T) >> 4)) << 20) + (((T) & 15) << 6);                \
    load_lds16(_g,          &Bs_[_s][0][(w * 8) * 64]);                  \
    load_lds16(_g + 65536,  &Bs_[_s][0][(64 + w * 8) * 64]);             \
    load_lds16(_g + 131072, &Bs_[_s][1][(w * 8) * 64]);                  \
    load_lds16(_g + 196608, &Bs_[_s][1][(64 + w * 8) * 64]);             \
  } while (0)

  // fragment read offsets: granule = (ks*4+lq) ^ (lr&7)  (conflict-free:
  // every consecutive-8-lane group covers all 8 granules)
  int ar0 = lr * 64 + (((0 * 4) + lq) ^ (lr & 7)) * 8;
  int ar1 = lr * 64 + (((1 * 4) + lq) ^ (lr & 7)) * 8;
  const unsigned short* pA = &As_[0][wr][0];
  const unsigned short* pB = &Bs_[0][wc >> 1][(wc & 1) * 4096];

#define FENCE asm volatile("" ::: "memory")
#define BAR do { FENCE; __builtin_amdgcn_s_barrier(); FENCE; } while (0)
#define LGKM0 asm volatile("s_waitcnt lgkmcnt(0)" ::: "memory")

#define RESCALE(H) do {                                                  \
    float _bh[4];                                                        \
    _Pragma("unroll") for (int n = 0; n < 4; n++)                        \
      _bh[n] = bvs[(H) * 256 + wc * 64 + 16 * n + lr];                   \
    _Pragma("unroll") for (int m = 0; m < 8; m++)                        \
      _Pragma("unroll") for (int r = 0; r < 4; r++) {                    \
        float _rr = Rs[(wr * 128 + 16 * m + 4 * lq + r) * 8 + (H)];      \
        _Pragma("unroll") for (int n = 0; n < 4; n++)                    \
          acc[m][n][r] = acc[m][n][r] * _rr + _bh[n];                    \
      } } while (0)

#define MM(AM, BN, AI, BI) do {                                          \
    acc[AM][BN] = __builtin_amdgcn_mfma_f32_16x16x32_bf16(               \
        AI[0], BI[0], acc[AM][BN], 0, 0, 0);                             \
    acc[AM][BN] = __builtin_amdgcn_mfma_f32_16x16x32_bf16(               \
        AI[1], BI[1], acc[AM][BN], 0, 0, 0);                             \
  } while (0)

#define PH_BODY(k, STG, VMSTMT) do {                                     \
    const int _sl = (k) & 1;                                             \
    const unsigned short* _pA = pA + _sl * 16384;                        \
    const unsigned short* _pB = pB + _sl * 16384;                        \
    short8 aF[4][2], bL[2][2], bH[2][2];                                 \
    /* q0: read A m0-3 + B n0-1; MFMA (mlo,nlo) */                       \
    _Pragma("unroll") for (int m = 0; m < 4; m++) {                      \
      aF[m][0] = *(const short8*)(_pA + m * 1024 + ar0);                 \
      aF[m][1] = *(const short8*)(_pA + m * 1024 + ar1);                 \
    }                                                                    \
    _Pragma("unroll") for (int n = 0; n < 2; n++) {                      \
      bL[n][0] = *(const short8*)(_pB + n * 1024 + ar0);                 \
      bL[n][1] = *(const short8*)(_pB + n * 1024 + ar1);                 \
    }                                                                    \
    BAR; LGKM0;                                                          \
    if ((((k) & 15) == 0) && (k)) RESCALE((k) >> 4);                     \
    __builtin_amdgcn_s_setprio(1);                                       \
    _Pragma("unroll") for (int m = 0; m < 4; m++)                        \
      _Pragma("unroll") for (int n = 0; n < 2; n++)                      \
        MM(m, n, aF[m], bL[n]);                                          \
    __builtin_amdgcn_s_setprio(0);                                       \
    BAR;                                                                 \
    /* q1: read B n2-3; MFMA (mlo,nhi) */                                \
    _Pragma("unroll") for (int n = 0; n < 2; n++) {                      \
      bH[n][0] = *(const short8*)(_pB + (n + 2) * 1024 + ar0);           \
      bH[n][1] = *(const short8*)(_pB + (n + 2) * 1024 + ar1);           \
    }                                                                    \
    BAR; LGKM0;                                                          \
    __builtin_amdgcn_s_setprio(1);                                       \
    _Pragma("unroll") for (int m = 0; m < 4; m++)                        \
      _Pragma("unroll") for (int n = 0; n < 2; n++)                      \
        MM(m, n + 2, aF[m], bH[n]);                                      \
    __builtin_amdgcn_s_setprio(0);                                       \
    BAR;                                                                 \
    /* q2: read A m4-7; stage B(k+2); MFMA (mhi,nhi) */                  \
    _Pragma("unroll") for (int m = 0; m < 4; m++) {                      \
      aF[m][0] = *(const short8*)(_pA + (m + 4) * 1024 + ar0);           \
      aF[m][1] = *(const short8*)(_pA + (m + 4) * 1024 + ar1);           \
    }                                                                    \
    if (STG) STAGE_B((k) + 2);                                           \
    BAR; LGKM0;                                                          \
    __builtin_amdgcn_s_setprio(1);                                       \
    _Pragma("unroll") for (int m = 0; m < 4; m++)                        \
      _Pragma("unroll") for (int n = 0; n < 2; n++)                      \
        MM(m + 4, n + 2, aF[m], bH[n]);                                  \
    __builtin_amdgcn_s_setprio(0);                                       \
    BAR;                                                                 \
    /* q3: stage A(k+2); counted vmcnt; MFMA (mhi,nlo) w/ bL from q0 */  \
    if (STG) STAGE_A((k) + 2);                                           \
    VMSTMT;                                                              \
    BAR;                                                                 \
    __builtin_amdgcn_s_setprio(1);                                       \
    _Pragma("unroll") for (int m = 0; m < 4; m++)                        \
      _Pragma("unroll") for (int n = 0; n < 2; n++)                      \
        MM(m + 4, n, aF[m], bL[n]);                                      \
    __builtin_amdgcn_s_setprio(0);                                       \
    BAR;                                                                 \
  } while (0)

  // prologue staging: K-tiles 0,1 (16 load-instructions); wait first 8
  STAGE_B(0); STAGE_A(0); STAGE_B(1); STAGE_A(1);
  asm volatile("s_waitcnt vmcnt(8)" ::: "memory");
  BAR;

  for (int k = 0; k < NKT - 2; ++k)
    PH_BODY(k, 1, asm volatile("s_waitcnt vmcnt(8)" ::: "memory"));
  PH_BODY(NKT - 2, 0, asm volatile("s_waitcnt vmcnt(0)" ::: "memory"));
  PH_BODY(NKT - 1, 0, ((void)0));

#undef PH_BODY
#undef MM
#undef RESCALE
#undef STAGE_A
#undef STAGE_B

  // epilogue: out = a_7 * S_7
#pragma unroll
  for (int m = 0; m < 8; m++)
#pragma unroll
    for (int r = 0; r < 4; r++) {
      int row = wr * 128 + 16 * m + 4 * lq + r;
      float fs = Rs[row * 8 + 0];
      float* op = out + (row0 + row) * (size_t)OUT_DIM + col0 + wc * 64 + lr;
#pragma unroll
      for (int n = 0; n < 4; n++) op[16 * n] = acc[m][n][r] * fs;
    }
}

// ---- legacy Phase 2 (float fallback only) ----
template<bool BF>
__launch_bounds__(256, 2)
__global__ void attn_phase2(const unsigned short* xb, const float* xf,
                            const unsigned short* wvb, const float* wvf,
                            const float* __restrict__ bv, const float* __restrict__ attn,
                            float* __restrict__ out) {
  __shared__ unsigned short Xs[128 * 64];
  __shared__ unsigned short Ws[128 * 64];
  __shared__ float As[128 * 8];
  __shared__ float bvs[8 * 128];
  int b = blockIdx.x;
  int bt = (b >> 6) * 8 + (b & 7);
  int ot = (b >> 3) & 7;
  size_t row0 = (size_t)bt * 128;
  int col0 = ot * 128;
  int tid = threadIdx.x;
  int w = tid >> 6, lane = tid & 63;
  int wr = w >> 1, wc = w & 1, lq = lane >> 4, lr = lane & 15;

  for (int i = tid; i < 1024; i += 256) {
    As[i]  = attn[row0 * 8 + i];
    bvs[i] = bv[(i >> 7) * OUT_DIM + col0 + (i & 127)];
  }
  __syncthreads();

  floatx4 oacc[4][4];
#pragma unroll
  for (int i = 0; i < 4; i++)
#pragma unroll
    for (int j = 0; j < 4; j++) oacc[i][j] = (floatx4){0.f, 0.f, 0.f, 0.f};

  for (int h = 0; h < N_HEADS; h++) {
    floatx4 acc[4][4];
#pragma unroll
    for (int i = 0; i < 4; i++)
#pragma unroll
      for (int j = 0; j < 4; j++) acc[i][j] = (floatx4){0.f, 0.f, 0.f, 0.f};
    for (int kt = 0; kt < IN_DIM; kt += 64) {
      stage_tile<BF>(xb, xf, IN_DIM, row0, kt, Xs, tid);
      if constexpr (BF)
        stage_tile<BF>(wvb + ((size_t)h * OUT_DIM + col0) * IN_DIM, nullptr, IN_DIM, 0, kt, Ws, tid);
      else
        stage_tile<BF>(nullptr, wvf + ((size_t)h * OUT_DIM + col0) * IN_DIM, IN_DIM, 0, kt, Ws, tid);
      __syncthreads();
      mma_tile(Xs, Ws, acc, wr, wc, lq, lr);
      __syncthreads();
    }
#pragma unroll
    for (int i = 0; i < 4; i++)
#pragma unroll
      for (int r = 0; r < 4; r++) {
        int row_l = 64 * wr + 16 * i + 4 * lq + r;
        float a = As[row_l * 8 + h];
#pragma unroll
        for (int j = 0; j < 4; j++) {
          int col_l = 64 * wc + 16 * j + lr;
          oacc[i][j][r] += a * (acc[i][j][r] + bvs[h * 128 + col_l]);
        }
      }
  }
#pragma unroll
  for (int i = 0; i < 4; i++)
#pragma unroll
    for (int r = 0; r < 4; r++) {
      int row_l = 64 * wr + 16 * i + 4 * lq + r;
#pragma unroll
      for (int j = 0; j < 4; j++) {
        int col_l = 64 * wc + 16 * j + lr;
        out[(row0 + row_l) * (size_t)OUT_DIM + col0 + col_l] = oacc[i][j][r];
      }
    }
}

// ---- fused phase 1 (fallback when ws can't hold Qb) ----
template<bool BF>
__launch_bounds__(256, 2)
__global__ void attn_phase1_fused(const unsigned short* xb, const float* xf,
                                  const unsigned short* wqb, const float* wqf,
                                  const unsigned short* wkb, const float* wkf,
                                  const float* bq, const float* bk, float* attn) {
  __shared__ unsigned short Xs[128 * 64];
  __shared__ unsigned short Ws[128 * 64];
  __shared__ unsigned short Qs[128 * 128];
  __shared__ float dots[128 * 8];
  int tid = threadIdx.x;
  size_t row0 = (size_t)blockIdx.x * 128;
  int w = tid >> 6, lane = tid & 63;
  int wr = w >> 1, wc = w & 1, lq = lane >> 4, lr = lane & 15;

  for (int i = tid; i < 1024; i += 256) dots[i] = 0.0f;

  floatx4 acc[4][4];
#pragma unroll
  for (int i = 0; i < 4; i++)
#pragma unroll
    for (int j = 0; j < 4; j++) acc[i][j] = (floatx4){0.f, 0.f, 0.f, 0.f};

  for (int kt = 0; kt < IN_DIM; kt += 64) {
    stage_tile<BF>(xb, xf, IN_DIM, row0, kt, Xs, tid);
    stage_tile<BF>(wqb, wqf, IN_DIM, 0, kt, Ws, tid);
    __syncthreads();
    mma_tile(Xs, Ws, acc, wr, wc, lq, lr);
    __syncthreads();
  }
#pragma unroll
  for (int i = 0; i < 4; i++)
#pragma unroll
    for (int j = 0; j < 4; j++)
#pragma unroll
      for (int r = 0; r < 4; r++) {
        int row_l = 64 * wr + 16 * i + 4 * lq + r;
        int col_l = 64 * wc + 16 * j + lr;
        Qs[row_l * 128 + col_l] = f2b(acc[i][j][r] + bq[col_l]);
      }
  __syncthreads();

  for (int h = 0; h < N_HEADS; h++) {
#pragma unroll
    for (int i = 0; i < 4; i++)
#pragma unroll
      for (int j = 0; j < 4; j++) acc[i][j] = (floatx4){0.f, 0.f, 0.f, 0.f};
    for (int kt = 0; kt < IN_DIM; kt += 64) {
      stage_tile<BF>(xb, xf, IN_DIM, row0, kt, Xs, tid);
      if constexpr (BF)
        stage_tile<BF>(wkb + (size_t)h * ATTN_DIM * IN_DIM, nullptr, IN_DIM, 0, kt, Ws, tid);
      else
        stage_tile<BF>(nullptr, wkf + (size_t)h * ATTN_DIM * IN_DIM, IN_DIM, 0, kt, Ws, tid);
      __syncthreads();
      mma_tile(Xs, Ws, acc, wr, wc, lq, lr);
      __syncthreads();
    }
#pragma unroll
    for (int i = 0; i < 4; i++)
#pragma unroll
      for (int r = 0; r < 4; r++) {
        int row_l = 64 * wr + 16 * i + 4 * lq + r;
        float p = 0.0f;
#pragma unroll
        for (int j = 0; j < 4; j++) {
          int col_l = 64 * wc + 16 * j + lr;
          p += (acc[i][j][r] + bk[h * ATTN_DIM + col_l]) * b2f(Qs[row_l * 128 + col_l]);
        }
        p += __shfl_xor(p, 1);
        p += __shfl_xor(p, 2);
        p += __shfl_xor(p, 4);
        p += __shfl_xor(p, 8);
        if (lr == 0) atomicAdd(&dots[row_l * 8 + h], p);
      }
    __syncthreads();
  }

  if (tid < 128) {
    float d[8];
    float m = -1e30f;
#pragma unroll
    for (int h = 0; h < 8; h++) {
      d[h] = dots[tid * 8 + h] * 0.088388347648318447f;
      m = fmaxf(m, d[h]);
    }
    float s = 0.f;
#pragma unroll
    for (int h = 0; h < 8; h++) { d[h] = __expf(d[h] - m); s += d[h]; }
    float inv = 1.0f / s;
    size_t rg = row0 + tid;
#pragma unroll
    for (int h = 0; h < 8; h++) attn[rg * 8 + h] = d[h] * inv;
  }
}

__global__ void cvt_bf16(const float4* __restrict__ in, ushort4* __restrict__ out, int n4) {
  int i = blockIdx.x * blockDim.x + threadIdx.x;
  int stride = gridDim.x * blockDim.x;
  for (; i < n4; i += stride) {
    float4 v = in[i];
    out[i] = make_ushort4(f2b(v.x), f2b(v.y), f2b(v.z), f2b(v.w));
  }
}

extern "C" void kernel_launch(void* const* d_in, const int* in_sizes, int n_in,
                              void* d_out, int out_size, void* d_ws, size_t ws_size,
                              hipStream_t stream) {
  const float* x  = (const float*)d_in[0];
  const float* Wq = (const float*)d_in[1];
  const float* bq = (const float*)d_in[2];
  const float* Wk = (const float*)d_in[3];
  const float* bk = (const float*)d_in[4];
  const float* Wv = (const float*)d_in[5];
  const float* bv = (const float*)d_in[6];
  float* out = (float*)d_out;

  // ws layout — d_out is NEVER used as scratch (its re-poison is not
  // reliably ordered against graph replays; see R2 post-mortem).
  char* ws = (char*)d_ws;
  float* attn = (float*)ws;                                        // dots -> attn in place
  size_t off = (size_t)BATCH * N_HEADS * 4;                        // 1 MB
  unsigned short* xb  = (unsigned short*)(ws + off); off += (size_t)BATCH * IN_DIM * 2;       // 64 MB
  unsigned short* wqb = (unsigned short*)(ws + off); off += (size_t)ATTN_DIM * IN_DIM * 2;    // 0.25 MB
  unsigned short* wkb = (unsigned short*)(ws + off); off += (size_t)N_HEADS * ATTN_DIM * IN_DIM * 2; // 2 MB
  unsigned short* wvb = (unsigned short*)(ws + off); off += (size_t)N_HEADS * OUT_DIM * IN_DIM * 2;  // 16 MB
  size_t off_noq = off;
  unsigned short* Qb  = (unsigned short*)(ws + off); off += (size_t)BATCH * ATTN_DIM * 2;     // 8 MB

  if (ws_size >= off_noq) {
    cvt_bf16<<<8192, 256, 0, stream>>>((const float4*)x,  (ushort4*)xb,  BATCH * IN_DIM / 4);
    cvt_bf16<<<128,  256, 0, stream>>>((const float4*)Wq, (ushort4*)wqb, ATTN_DIM * IN_DIM / 4);
    cvt_bf16<<<1024, 256, 0, stream>>>((const float4*)Wk, (ushort4*)wkb, N_HEADS * ATTN_DIM * IN_DIM / 4);
    cvt_bf16<<<8192, 256, 0, stream>>>((const float4*)Wv, (ushort4*)wvb, N_HEADS * OUT_DIM * IN_DIM / 4);
    if (ws_size >= off) {
      q_gemm<<<BATCH / 128, 256, 0, stream>>>(xb, wqb, bq, Qb);
      k_dot<<<(BATCH / 128) * N_HEADS, 256, 0, stream>>>(xb, wkb, Qb, bk, attn);
      softmax8<<<BATCH / 256, 256, 0, stream>>>(attn);
    } else {
      attn_phase1_fused<true><<<BATCH / 128, 256, 0, stream>>>(
          xb, nullptr, wqb, nullptr, wkb, nullptr, bq, bk, attn);
    }
    attn_phase2_8p<<<(BATCH / 256) * (OUT_DIM / 256), 512, 0, stream>>>(
        xb, wvb, bv, attn, out);
  } else {
    attn_phase1_fused<false><<<BATCH / 128, 256, 0, stream>>>(
        nullptr, x, nullptr, Wq, nullptr, Wk, bq, bk, attn);
    attn_phase2<false><<<(BATCH / 128) * (OUT_DIM / 128), 256, 0, stream>>>(
        nullptr, x, nullptr, Wv, bv, attn, out);
  }
}